// Round 2
// baseline (1167.893 us; speedup 1.0000x reference)
//
#include <hip/hip_runtime.h>
#include <hip/hip_fp16.h>

// Problem constants (reference: B=16, T=2048, D=768)
#define DD 768
#define BB 16
#define TT 2048
#define BT (BB*TT)   // 32768

using u16 = unsigned short;
using f16 = _Float16;
typedef __attribute__((ext_vector_type(8))) f16 half8;   // MFMA A/B frag (4 VGPR)
typedef __attribute__((ext_vector_type(4))) f16 half4;   // 8B store
typedef __attribute__((ext_vector_type(4))) float f32x4; // MFMA C/D frag

typedef const __attribute__((address_space(1))) unsigned int* gas1;
typedef __attribute__((address_space(3))) unsigned int* las3;
__device__ __forceinline__ void gload16(const void* g, void* l){
  // async global->LDS, 16B per lane; LDS dest linear in lane order (wave base + lane*16)
  __builtin_amdgcn_global_load_lds((gas1)g, (las3)l, 16, 0, 0);
}

// ---------------- fp32 -> fp16 ----------------
__global__ __launch_bounds__(256)
void tofp16_kernel(const float* __restrict__ src, f16* __restrict__ dst, int n4){
  const int stride = gridDim.x * 256;
  for (int i = blockIdx.x*256 + threadIdx.x; i < n4; i += stride){
    float4 v = ((const float4*)src)[i];
    half4 h; h[0]=(f16)v.x; h[1]=(f16)v.y; h[2]=(f16)v.z; h[3]=(f16)v.w;
    ((half4*)dst)[i] = h;
  }
}

// ---------------- NT GEMM: C[m,n] = sum_k A[m,k]*B[n,k], fp16 in, fp32 acc ----------
// OMODE 0: out f16 = acc + bias[n]        (projections; gridDim.z==1)
// OMODE 1: out f32 = acc                  (logits S)
// OMODE 2: out f32 = acc + res[flat]      (PV + residual x)
template<int OMODE>
__global__ __launch_bounds__(256)
void gemm_nt(const f16* __restrict__ A, int lda, long sA,
             const f16* __restrict__ B, int ldb, long sB,
             void* __restrict__ Out, int ldc, long sC,
             const float* __restrict__ aux, int Kdim)
{
  const int b = blockIdx.z;
  const f16* A_ = A + (size_t)b * sA;
  const f16* B_ = B + (size_t)b * sB;
  const int m0 = blockIdx.x * 128, n0 = blockIdx.y * 128;
  const int tid = threadIdx.x, lane = tid & 63;
  const int wm = (tid >> 6) >> 1, wn = (tid >> 6) & 1;

  __shared__ f16 lA[128*32];
  __shared__ f16 lB[128*32];

  f32x4 acc[4][4] = {};

  for (int kt = 0; kt < Kdim; kt += 32){
#pragma unroll
    for (int i = 0; i < 2; ++i){
      int c = i*256 + tid;               // 512 x 16B chunks per 128x32 f16 tile
      int r = c >> 2, col = (c & 3) * 8;
      gload16(A_ + (size_t)(m0 + r) * lda + kt + col, &lA[c*8]);
      gload16(B_ + (size_t)(n0 + r) * ldb + kt + col, &lB[c*8]);
    }
    __syncthreads();   // compiler drains vmcnt before s_barrier

    const int frow = lane & 15, kq = (lane >> 4) * 8;
    half8 af[4], bfr[4];
#pragma unroll
    for (int i = 0; i < 4; ++i){
      af[i]  = *(const half8*)&lA[(wm*64 + i*16 + frow)*32 + kq];
      bfr[i] = *(const half8*)&lB[(wn*64 + i*16 + frow)*32 + kq];
    }
#pragma unroll
    for (int i = 0; i < 4; ++i)
#pragma unroll
      for (int j = 0; j < 4; ++j)
        acc[i][j] = __builtin_amdgcn_mfma_f32_16x16x32_f16(af[i], bfr[j], acc[i][j], 0,0,0);
    __syncthreads();
  }

  // C/D layout: col = lane&15, row = (lane>>4)*4 + r   [m89 verified]
#pragma unroll
  for (int i = 0; i < 4; ++i)
#pragma unroll
    for (int j = 0; j < 4; ++j){
      const int gc = n0 + wn*64 + j*16 + (lane & 15);
      float bias_v = 0.f;
      if constexpr (OMODE == 0) bias_v = aux[gc];
#pragma unroll
      for (int r = 0; r < 4; ++r){
        const int gr = m0 + wm*64 + i*16 + (lane >> 4)*4 + r;
        float v = acc[i][j][r];
        if constexpr (OMODE == 0){
          ((f16*)Out)[(size_t)gr*ldc + gc] = (f16)(v + bias_v);
        } else if constexpr (OMODE == 1){
          ((float*)Out)[(size_t)b*sC + (size_t)gr*ldc + gc] = v;
        } else {
          size_t o = (size_t)b*sC + (size_t)gr*ldc + gc;
          ((float*)Out)[o] = v + aux[o];   // aux = residual x chunk, same flat layout
        }
      }
    }
}

// ---------------- column softmax stats over q for each (b_local, t) ----------------
__global__ __launch_bounds__(256)
void stats_kernel(const float* __restrict__ S, float* __restrict__ mcol,
                  float* __restrict__ zinv){
  const int b = blockIdx.y;                 // local batch in chunk
  const int tl = threadIdx.x & 63;
  const int qp = threadIdx.x >> 6;          // 4 q-partials per column
  const int t = blockIdx.x * 64 + tl;
  const float* Sb = S + (size_t)b * TT * TT;
  float m = -3.0e38f, Z = 0.f;
  for (int q = qp; q < TT; q += 4){
    float s = Sb[(size_t)q * TT + t];       // consecutive t across lanes: coalesced
    float nm = fmaxf(m, s);
    Z = Z * __expf(m - nm) + __expf(s - nm);
    m = nm;
  }
  __shared__ float sm[4][64], sz[4][64];
  sm[qp][tl] = m; sz[qp][tl] = Z;
  __syncthreads();
  if (qp == 0){
    float M = sm[0][tl];
#pragma unroll
    for (int k = 1; k < 4; ++k) M = fmaxf(M, sm[k][tl]);
    float Zt = 0.f;
#pragma unroll
    for (int k = 0; k < 4; ++k) Zt += sz[k][tl] * __expf(sm[k][tl] - M);
    mcol[b*TT + t] = M;
    zinv[b*TT + t] = 1.f / (Zt * 27.712812921102035f);  // 1/(Z*sqrt(768))
  }
}

// ---------------- P = exp(S - m_t) * zinv_t -> f16 ----------------
__global__ __launch_bounds__(256)
void pexp_kernel(const float* __restrict__ S, const float* __restrict__ mcol,
                 const float* __restrict__ zinv, f16* __restrict__ P, int G){
  const int n4 = G * (TT*TT/4);
  const int stride = gridDim.x * 256;
  for (int i = blockIdx.x*256 + threadIdx.x; i < n4; i += stride){
    float4 s4 = ((const float4*)S)[i];
    int t   = (i*4) & (TT - 1);
    int row = (int)(((size_t)i * 4) >> 11);   // global row in chunk
    int b   = row >> 11;                      // local batch
    int bt = b * TT + t;
    float4 m4 = *(const float4*)&mcol[bt];
    float4 z4 = *(const float4*)&zinv[bt];
    half4 o;
    o[0] = (f16)(__expf(s4.x - m4.x) * z4.x);
    o[1] = (f16)(__expf(s4.y - m4.y) * z4.y);
    o[2] = (f16)(__expf(s4.z - m4.z) * z4.z);
    o[3] = (f16)(__expf(s4.w - m4.w) * z4.w);
    ((half4*)P)[i] = o;
  }
}

// ---------------- V [t,v] -> Vt [v,t] (per local batch) ----------------
__global__ __launch_bounds__(256)
void transp_kernel(const u16* __restrict__ V, u16* __restrict__ Vt){
  const int b = blockIdx.z;
  const int t0 = blockIdx.x * 64, v0 = blockIdx.y * 64;
  const u16* Vb = V + (size_t)b * TT * DD;
  u16* Vtb = Vt + (size_t)b * DD * TT;
  __shared__ u16 tile[64][66];
  const int tid = threadIdx.x;
#pragma unroll
  for (int i = 0; i < 4; ++i){
    int c = i*256 + tid;
    int r = c >> 4, c4 = (c & 15) * 4;
    ushort4 u = *(const ushort4*)&Vb[(size_t)(t0 + r) * DD + v0 + c4];
    tile[r][c4+0] = u.x; tile[r][c4+1] = u.y; tile[r][c4+2] = u.z; tile[r][c4+3] = u.w;
  }
  __syncthreads();
#pragma unroll
  for (int i = 0; i < 4; ++i){
    int c = i*256 + tid;
    int vr = c >> 4, t4 = (c & 15) * 4;
    ushort4 u;
    u.x = tile[t4+0][vr]; u.y = tile[t4+1][vr]; u.z = tile[t4+2][vr]; u.w = tile[t4+3][vr];
    *(ushort4*)&Vtb[(size_t)(v0 + vr) * TT + t0 + t4] = u;
  }
}

// ---------------- LayerNorm (in-place on d_out), one row per block ----------------
__global__ __launch_bounds__(256)
void ln_kernel(float* __restrict__ y, const float* __restrict__ gamma,
               const float* __restrict__ beta){
  const int row = blockIdx.x;
  float* p = y + (size_t)row * DD;
  const int tid = threadIdx.x;
  float v[3]; float s = 0.f, sq = 0.f;
#pragma unroll
  for (int k = 0; k < 3; ++k){
    v[k] = p[tid + k*256];
    s += v[k]; sq += v[k]*v[k];
  }
#pragma unroll
  for (int off = 32; off > 0; off >>= 1){
    s  += __shfl_down(s,  off, 64);
    sq += __shfl_down(sq, off, 64);
  }
  __shared__ float red[8];
  const int lane = tid & 63, w = tid >> 6;
  if (lane == 0){ red[w] = s; red[4+w] = sq; }
  __syncthreads();
  if (tid == 0){
    red[0] = red[0]+red[1]+red[2]+red[3];
    red[4] = red[4]+red[5]+red[6]+red[7];
  }
  __syncthreads();
  const float mu  = red[0] * (1.f/DD);
  const float var = red[4] * (1.f/DD) - mu*mu;
  const float rs  = rsqrtf(var + 1e-5f);
#pragma unroll
  for (int k = 0; k < 3; ++k){
    int c = tid + k*256;
    p[c] = (v[k] - mu) * rs * gamma[c] + beta[c];
  }
}

extern "C" void kernel_launch(void* const* d_in, const int* in_sizes, int n_in,
                              void* d_out, int out_size, void* d_ws, size_t ws_size,
                              hipStream_t stream)
{
  // setup_inputs order: x, Wk, bk, Wq, bq, Wv, bv, gamma, beta
  const float* x    = (const float*)d_in[0];
  const float* Wk   = (const float*)d_in[1];
  const float* bk   = (const float*)d_in[2];
  const float* Wq   = (const float*)d_in[3];
  const float* bq   = (const float*)d_in[4];
  const float* Wv   = (const float*)d_in[5];
  const float* bv   = (const float*)d_in[6];
  const float* gamma= (const float*)d_in[7];
  const float* beta = (const float*)d_in[8];
  float* out = (float*)d_out;

  const size_t PW  = (size_t)DD*DD*2;   // f16 weight plane
  const size_t PB  = (size_t)TT*DD*2;   // f16 activation plane per batch
  const size_t SB  = (size_t)TT*TT*4;   // f32 S per batch
  const size_t PP  = (size_t)TT*TT*2;   // f16 P per batch
  const size_t TB4 = (size_t)TT*4;

  auto need = [&](int G)->size_t{
    size_t t = 0;
    auto add = [&](size_t n){ t += (n + 255) & ~(size_t)255; };
    add(PW); add(PW); add(PW);
    for (int k = 0; k < 5; ++k) add((size_t)G * PB);   // Xc,Qc,Kc,Vc,Vtc
    add((size_t)G * SB); add((size_t)G * PP);
    add((size_t)G * TB4); add((size_t)G * TB4);
    return t;
  };

  // diagnostic canary: out = x (overwritten by the real pipeline if it runs)
  hipMemcpyAsync(out, x, (size_t)BT*DD*sizeof(float), hipMemcpyDeviceToDevice, stream);

  int G = 16;
  while (G > 1 && need(G) > ws_size) G >>= 1;
  if (need(G) > ws_size) return;   // absmax would be |ref - x|max, not |ref|max

  char* p = (char*)d_ws;
  auto alloc = [&](size_t n)->char*{ char* r = p; p += (n + 255) & ~(size_t)255; return r; };
  f16*   Wqf  = (f16*)alloc(PW);
  f16*   Wkf  = (f16*)alloc(PW);
  f16*   Wvf  = (f16*)alloc(PW);
  f16*   Xc   = (f16*)alloc((size_t)G * PB);
  f16*   Qc   = (f16*)alloc((size_t)G * PB);
  f16*   Kc   = (f16*)alloc((size_t)G * PB);
  f16*   Vc   = (f16*)alloc((size_t)G * PB);
  f16*   Vtc  = (f16*)alloc((size_t)G * PB);
  float* Sc   = (float*)alloc((size_t)G * SB);
  f16*   Pc   = (f16*)alloc((size_t)G * PP);
  float* mcol = (float*)alloc((size_t)G * TB4);
  float* zinv = (float*)alloc((size_t)G * TB4);

  tofp16_kernel<<<288, 256, 0, stream>>>(Wq, Wqf, DD*DD/4);
  tofp16_kernel<<<288, 256, 0, stream>>>(Wk, Wkf, DD*DD/4);
  tofp16_kernel<<<288, 256, 0, stream>>>(Wv, Wvf, DD*DD/4);

  const int nRows = G * TT;
  for (int b0 = 0; b0 < BB; b0 += G){
    tofp16_kernel<<<2048, 256, 0, stream>>>(x + (size_t)b0*TT*DD, Xc, nRows*DD/4);

    dim3 gp(nRows/128, DD/128, 1);
    gemm_nt<0><<<gp, 256, 0, stream>>>(Xc, DD, 0, Wqf, DD, 0, Qc, DD, 0, bq, DD);
    gemm_nt<0><<<gp, 256, 0, stream>>>(Xc, DD, 0, Wkf, DD, 0, Kc, DD, 0, bk, DD);
    gemm_nt<0><<<gp, 256, 0, stream>>>(Xc, DD, 0, Wvf, DD, 0, Vc, DD, 0, bv, DD);

    transp_kernel<<<dim3(TT/64, DD/64, G), 256, 0, stream>>>((const u16*)Vc, (u16*)Vtc);

    dim3 gs(TT/128, TT/128, G);
    gemm_nt<1><<<gs, 256, 0, stream>>>(Qc, DD, (long)TT*DD, Kc, DD, (long)TT*DD,
                                       Sc, TT, (long)TT*TT, nullptr, DD);

    stats_kernel<<<dim3(TT/64, G), 256, 0, stream>>>(Sc, mcol, zinv);
    pexp_kernel<<<2048, 256, 0, stream>>>(Sc, mcol, zinv, Pc, G);

    dim3 gpv(TT/128, DD/128, G);
    gemm_nt<2><<<gpv, 256, 0, stream>>>(Pc, TT, (long)TT*TT, Vtc, TT, (long)DD*TT,
                                        out + (size_t)b0*TT*DD, DD, (long)TT*DD,
                                        x + (size_t)b0*TT*DD, TT);
  }

  ln_kernel<<<BT, 256, 0, stream>>>(out, gamma, beta);
}

// Round 3
// 854.927 us; speedup vs baseline: 1.3661x; 1.3661x over previous
//
#include <hip/hip_runtime.h>
#include <hip/hip_fp16.h>

// Problem constants (reference: B=16, T=2048, D=768)
#define DD 768
#define BB 16
#define TT 2048
#define BT (BB*TT)   // 32768
#define NQC 16       // q-chunks for parallel column-softmax stats

using u16 = unsigned short;
using f16 = _Float16;
typedef __attribute__((ext_vector_type(8))) f16 half8;   // MFMA A/B frag (4 VGPR)
typedef __attribute__((ext_vector_type(4))) f16 half4;   // 8B store
typedef __attribute__((ext_vector_type(4))) float f32x4; // MFMA C/D frag

typedef const __attribute__((address_space(1))) unsigned int* gas1;
typedef __attribute__((address_space(3))) unsigned int* las3;
__device__ __forceinline__ void gload16(const void* g, void* l){
  // async global->LDS, 16B per lane; LDS dest linear in lane order (wave base + lane*16)
  __builtin_amdgcn_global_load_lds((gas1)g, (las3)l, 16, 0, 0);
}

// ---------------- fp32 -> fp16 ----------------
__global__ __launch_bounds__(256)
void tofp16_kernel(const float* __restrict__ src, f16* __restrict__ dst, int n4){
  const int stride = gridDim.x * 256;
  for (int i = blockIdx.x*256 + threadIdx.x; i < n4; i += stride){
    float4 v = ((const float4*)src)[i];
    half4 h; h[0]=(f16)v.x; h[1]=(f16)v.y; h[2]=(f16)v.z; h[3]=(f16)v.w;
    ((half4*)dst)[i] = h;
  }
}

// ---------------- NT GEMM: C[m,n] = sum_k A[m,k]*B[n,k], fp16 in, fp32 acc ----------
// OMODE 0: out f16 = acc + bias[n]        (projections; gridDim.z==1)
// OMODE 1: out f32 = acc                  (logits S)
// OMODE 2: out f32 = acc + res[flat]      (PV + residual x)
template<int OMODE>
__global__ __launch_bounds__(256)
void gemm_nt(const f16* __restrict__ A, int lda, long sA,
             const f16* __restrict__ B, int ldb, long sB,
             void* __restrict__ Out, int ldc, long sC,
             const float* __restrict__ aux, int Kdim)
{
  const int b = blockIdx.z;
  const f16* A_ = A + (size_t)b * sA;
  const f16* B_ = B + (size_t)b * sB;
  const int m0 = blockIdx.x * 128, n0 = blockIdx.y * 128;
  const int tid = threadIdx.x, lane = tid & 63;
  const int wm = (tid >> 6) >> 1, wn = (tid >> 6) & 1;

  __shared__ f16 lA[128*32];
  __shared__ f16 lB[128*32];

  f32x4 acc[4][4] = {};

  for (int kt = 0; kt < Kdim; kt += 32){
#pragma unroll
    for (int i = 0; i < 2; ++i){
      int c = i*256 + tid;               // 512 x 16B chunks per 128x32 f16 tile
      int r = c >> 2, col = (c & 3) * 8;
      gload16(A_ + (size_t)(m0 + r) * lda + kt + col, &lA[c*8]);
      gload16(B_ + (size_t)(n0 + r) * ldb + kt + col, &lB[c*8]);
    }
    __syncthreads();   // compiler drains vmcnt before s_barrier

    const int frow = lane & 15, kq = (lane >> 4) * 8;
    half8 af[4], bfr[4];
#pragma unroll
    for (int i = 0; i < 4; ++i){
      af[i]  = *(const half8*)&lA[(wm*64 + i*16 + frow)*32 + kq];
      bfr[i] = *(const half8*)&lB[(wn*64 + i*16 + frow)*32 + kq];
    }
#pragma unroll
    for (int i = 0; i < 4; ++i)
#pragma unroll
      for (int j = 0; j < 4; ++j)
        acc[i][j] = __builtin_amdgcn_mfma_f32_16x16x32_f16(af[i], bfr[j], acc[i][j], 0,0,0);
    __syncthreads();
  }

  // C/D layout: col = lane&15, row = (lane>>4)*4 + r   [m89 verified]
#pragma unroll
  for (int i = 0; i < 4; ++i)
#pragma unroll
    for (int j = 0; j < 4; ++j){
      const int gc = n0 + wn*64 + j*16 + (lane & 15);
      float bias_v = 0.f;
      if constexpr (OMODE == 0) bias_v = aux[gc];
#pragma unroll
      for (int r = 0; r < 4; ++r){
        const int gr = m0 + wm*64 + i*16 + (lane >> 4)*4 + r;
        float v = acc[i][j][r];
        if constexpr (OMODE == 0){
          ((f16*)Out)[(size_t)gr*ldc + gc] = (f16)(v + bias_v);
        } else if constexpr (OMODE == 1){
          ((float*)Out)[(size_t)b*sC + (size_t)gr*ldc + gc] = v;
        } else {
          size_t o = (size_t)b*sC + (size_t)gr*ldc + gc;
          ((float*)Out)[o] = v + aux[o];   // aux = residual x chunk, same flat layout
        }
      }
    }
}

// ------- column softmax stats, phase A: partial (m,Z) per (b, qchunk, t) -------
// grid: (TT/64, NQC, G)  block 256. Each block: 128 q-rows x 64 t-cols stripe.
__global__ __launch_bounds__(256)
void statsA_kernel(const float* __restrict__ S, float* __restrict__ pm,
                   float* __restrict__ pz){
  const int b = blockIdx.z;
  const int qc = blockIdx.y;
  const int tl = threadIdx.x & 63;
  const int qp = threadIdx.x >> 6;          // 4 q-partials per column
  const int t = blockIdx.x * 64 + tl;
  const float* Sb = S + (size_t)b * TT * TT;
  const int q0 = qc * (TT / NQC);
  float m = -3.0e38f, Z = 0.f;
#pragma unroll 8
  for (int q = q0 + qp; q < q0 + TT/NQC; q += 4){
    float s = Sb[(size_t)q * TT + t];       // 64 consecutive t across lanes: coalesced
    float nm = fmaxf(m, s);
    Z = Z * __expf(m - nm) + __expf(s - nm);
    m = nm;
  }
  __shared__ float sm[4][64], sz[4][64];
  sm[qp][tl] = m; sz[qp][tl] = Z;
  __syncthreads();
  if (qp == 0){
    float M = sm[0][tl];
#pragma unroll
    for (int k = 1; k < 4; ++k) M = fmaxf(M, sm[k][tl]);
    float Zt = 0.f;
#pragma unroll
    for (int k = 0; k < 4; ++k) Zt += sz[k][tl] * __expf(sm[k][tl] - M);
    size_t o = ((size_t)b * NQC + qc) * TT + t;
    pm[o] = M;
    pz[o] = Zt;
  }
}

// ------- phase B: merge NQC partials per column -> mcol, zinv -------
// grid: (TT/256, G)  block 256, one t per thread.
__global__ __launch_bounds__(256)
void statsB_kernel(const float* __restrict__ pm, const float* __restrict__ pz,
                   float* __restrict__ mcol, float* __restrict__ zinv){
  const int b = blockIdx.y;
  const int t = blockIdx.x * 256 + threadIdx.x;
  float M = -3.0e38f;
#pragma unroll
  for (int k = 0; k < NQC; ++k)
    M = fmaxf(M, pm[((size_t)b * NQC + k) * TT + t]);
  float Z = 0.f;
#pragma unroll
  for (int k = 0; k < NQC; ++k){
    size_t o = ((size_t)b * NQC + k) * TT + t;
    Z += pz[o] * __expf(pm[o] - M);
  }
  mcol[b*TT + t] = M;
  zinv[b*TT + t] = 1.f / (Z * 27.712812921102035f);  // 1/(Z*sqrt(768))
}

// ---------------- P = exp(S - m_t) * zinv_t -> f16 ----------------
__global__ __launch_bounds__(256)
void pexp_kernel(const float* __restrict__ S, const float* __restrict__ mcol,
                 const float* __restrict__ zinv, f16* __restrict__ P, int G){
  const int n4 = G * (TT*TT/4);
  const int stride = gridDim.x * 256;
  for (int i = blockIdx.x*256 + threadIdx.x; i < n4; i += stride){
    float4 s4 = ((const float4*)S)[i];
    int t   = (i*4) & (TT - 1);
    int row = (int)(((size_t)i * 4) >> 11);   // global row in chunk
    int b   = row >> 11;                      // local batch
    int bt = b * TT + t;
    float4 m4 = *(const float4*)&mcol[bt];
    float4 z4 = *(const float4*)&zinv[bt];
    half4 o;
    o[0] = (f16)(__expf(s4.x - m4.x) * z4.x);
    o[1] = (f16)(__expf(s4.y - m4.y) * z4.y);
    o[2] = (f16)(__expf(s4.z - m4.z) * z4.z);
    o[3] = (f16)(__expf(s4.w - m4.w) * z4.w);
    ((half4*)P)[i] = o;
  }
}

// ---------------- V [t,v] -> Vt [v,t] (per local batch) ----------------
__global__ __launch_bounds__(256)
void transp_kernel(const u16* __restrict__ V, u16* __restrict__ Vt){
  const int b = blockIdx.z;
  const int t0 = blockIdx.x * 64, v0 = blockIdx.y * 64;
  const u16* Vb = V + (size_t)b * TT * DD;
  u16* Vtb = Vt + (size_t)b * DD * TT;
  __shared__ u16 tile[64][66];
  const int tid = threadIdx.x;
#pragma unroll
  for (int i = 0; i < 4; ++i){
    int c = i*256 + tid;
    int r = c >> 4, c4 = (c & 15) * 4;
    ushort4 u = *(const ushort4*)&Vb[(size_t)(t0 + r) * DD + v0 + c4];
    tile[r][c4+0] = u.x; tile[r][c4+1] = u.y; tile[r][c4+2] = u.z; tile[r][c4+3] = u.w;
  }
  __syncthreads();
#pragma unroll
  for (int i = 0; i < 4; ++i){
    int c = i*256 + tid;
    int vr = c >> 4, t4 = (c & 15) * 4;
    ushort4 u;
    u.x = tile[t4+0][vr]; u.y = tile[t4+1][vr]; u.z = tile[t4+2][vr]; u.w = tile[t4+3][vr];
    *(ushort4*)&Vtb[(size_t)(v0 + vr) * TT + t0 + t4] = u;
  }
}

// ---------------- LayerNorm (in-place on d_out), one row per block ----------------
__global__ __launch_bounds__(256)
void ln_kernel(float* __restrict__ y, const float* __restrict__ gamma,
               const float* __restrict__ beta){
  const int row = blockIdx.x;
  float* p = y + (size_t)row * DD;
  const int tid = threadIdx.x;
  float v[3]; float s = 0.f, sq = 0.f;
#pragma unroll
  for (int k = 0; k < 3; ++k){
    v[k] = p[tid + k*256];
    s += v[k]; sq += v[k]*v[k];
  }
#pragma unroll
  for (int off = 32; off > 0; off >>= 1){
    s  += __shfl_down(s,  off, 64);
    sq += __shfl_down(sq, off, 64);
  }
  __shared__ float red[8];
  const int lane = tid & 63, w = tid >> 6;
  if (lane == 0){ red[w] = s; red[4+w] = sq; }
  __syncthreads();
  if (tid == 0){
    red[0] = red[0]+red[1]+red[2]+red[3];
    red[4] = red[4]+red[5]+red[6]+red[7];
  }
  __syncthreads();
  const float mu  = red[0] * (1.f/DD);
  const float var = red[4] * (1.f/DD) - mu*mu;
  const float rs  = rsqrtf(var + 1e-5f);
#pragma unroll
  for (int k = 0; k < 3; ++k){
    int c = tid + k*256;
    p[c] = (v[k] - mu) * rs * gamma[c] + beta[c];
  }
}

extern "C" void kernel_launch(void* const* d_in, const int* in_sizes, int n_in,
                              void* d_out, int out_size, void* d_ws, size_t ws_size,
                              hipStream_t stream)
{
  // setup_inputs order: x, Wk, bk, Wq, bq, Wv, bv, gamma, beta
  const float* x    = (const float*)d_in[0];
  const float* Wk   = (const float*)d_in[1];
  const float* bk   = (const float*)d_in[2];
  const float* Wq   = (const float*)d_in[3];
  const float* bq   = (const float*)d_in[4];
  const float* Wv   = (const float*)d_in[5];
  const float* bv   = (const float*)d_in[6];
  const float* gamma= (const float*)d_in[7];
  const float* beta = (const float*)d_in[8];
  float* out = (float*)d_out;

  const size_t PW  = (size_t)DD*DD*2;   // f16 weight plane
  const size_t PB  = (size_t)TT*DD*2;   // f16 activation plane per batch
  const size_t SB  = (size_t)TT*TT*4;   // f32 S per batch
  const size_t PP  = (size_t)TT*TT*2;   // f16 P per batch
  const size_t TB4 = (size_t)TT*4;

  auto need = [&](int G)->size_t{
    size_t t = 0;
    auto add = [&](size_t n){ t += (n + 255) & ~(size_t)255; };
    add(PW); add(PW); add(PW);
    for (int k = 0; k < 5; ++k) add((size_t)G * PB);   // Xc,Qc,Kc,Vc,Vtc
    add((size_t)G * SB); add((size_t)G * PP);
    add((size_t)G * NQC * TB4); add((size_t)G * NQC * TB4);   // pm, pz
    add((size_t)G * TB4); add((size_t)G * TB4);               // mcol, zinv
    return t;
  };

  int G = 16;
  while (G > 1 && need(G) > ws_size) G >>= 1;
  if (need(G) > ws_size) return;

  char* p = (char*)d_ws;
  auto alloc = [&](size_t n)->char*{ char* r = p; p += (n + 255) & ~(size_t)255; return r; };
  f16*   Wqf  = (f16*)alloc(PW);
  f16*   Wkf  = (f16*)alloc(PW);
  f16*   Wvf  = (f16*)alloc(PW);
  f16*   Xc   = (f16*)alloc((size_t)G * PB);
  f16*   Qc   = (f16*)alloc((size_t)G * PB);
  f16*   Kc   = (f16*)alloc((size_t)G * PB);
  f16*   Vc   = (f16*)alloc((size_t)G * PB);
  f16*   Vtc  = (f16*)alloc((size_t)G * PB);
  float* Sc   = (float*)alloc((size_t)G * SB);
  f16*   Pc   = (f16*)alloc((size_t)G * PP);
  float* pm   = (float*)alloc((size_t)G * NQC * TB4);
  float* pz   = (float*)alloc((size_t)G * NQC * TB4);
  float* mcol = (float*)alloc((size_t)G * TB4);
  float* zinv = (float*)alloc((size_t)G * TB4);

  tofp16_kernel<<<288, 256, 0, stream>>>(Wq, Wqf, DD*DD/4);
  tofp16_kernel<<<288, 256, 0, stream>>>(Wk, Wkf, DD*DD/4);
  tofp16_kernel<<<288, 256, 0, stream>>>(Wv, Wvf, DD*DD/4);

  const int nRows = G * TT;
  for (int b0 = 0; b0 < BB; b0 += G){
    tofp16_kernel<<<2048, 256, 0, stream>>>(x + (size_t)b0*TT*DD, Xc, nRows*DD/4);

    dim3 gp(nRows/128, DD/128, 1);
    gemm_nt<0><<<gp, 256, 0, stream>>>(Xc, DD, 0, Wqf, DD, 0, Qc, DD, 0, bq, DD);
    gemm_nt<0><<<gp, 256, 0, stream>>>(Xc, DD, 0, Wkf, DD, 0, Kc, DD, 0, bk, DD);
    gemm_nt<0><<<gp, 256, 0, stream>>>(Xc, DD, 0, Wvf, DD, 0, Vc, DD, 0, bv, DD);

    transp_kernel<<<dim3(TT/64, DD/64, G), 256, 0, stream>>>((const u16*)Vc, (u16*)Vtc);

    dim3 gs(TT/128, TT/128, G);
    gemm_nt<1><<<gs, 256, 0, stream>>>(Qc, DD, (long)TT*DD, Kc, DD, (long)TT*DD,
                                       Sc, TT, (long)TT*TT, nullptr, DD);

    statsA_kernel<<<dim3(TT/64, NQC, G), 256, 0, stream>>>(Sc, pm, pz);
    statsB_kernel<<<dim3(TT/256, G), 256, 0, stream>>>(pm, pz, mcol, zinv);
    pexp_kernel<<<2048, 256, 0, stream>>>(Sc, mcol, zinv, Pc, G);

    dim3 gpv(TT/128, DD/128, G);
    gemm_nt<2><<<gpv, 256, 0, stream>>>(Pc, TT, (long)TT*TT, Vtc, TT, (long)DD*TT,
                                        out + (size_t)b0*TT*DD, DD, (long)TT*DD,
                                        x + (size_t)b0*TT*DD, TT);
  }

  ln_kernel<<<BT, 256, 0, stream>>>(out, gamma, beta);
}

// Round 4
// 851.608 us; speedup vs baseline: 1.3714x; 1.0039x over previous
//
#include <hip/hip_runtime.h>
#include <hip/hip_fp16.h>

// Problem constants (reference: B=16, T=2048, D=768)
#define DD 768
#define BB 16
#define TT 2048
#define BT (BB*TT)   // 32768
#define NQC 16       // row-block partials per batch for column-softmax stats

using u16 = unsigned short;
using f16 = _Float16;
typedef __attribute__((ext_vector_type(8))) f16 half8;   // MFMA A/B frag (4 VGPR)
typedef __attribute__((ext_vector_type(4))) f16 half4;   // 8B store
typedef __attribute__((ext_vector_type(4))) float f32x4; // MFMA C/D frag

typedef const __attribute__((address_space(1))) unsigned int* gas1;
typedef __attribute__((address_space(3))) unsigned int* las3;
__device__ __forceinline__ void gload16(const void* g, void* l){
  // async global->LDS, 16B per lane; LDS dest linear in lane order (wave base + lane*16)
  __builtin_amdgcn_global_load_lds((gas1)g, (las3)l, 16, 0, 0);
}

// ---------------- fp32 -> fp16 ----------------
__global__ __launch_bounds__(256)
void tofp16_kernel(const float* __restrict__ src, f16* __restrict__ dst, int n4){
  const int stride = gridDim.x * 256;
  for (int i = blockIdx.x*256 + threadIdx.x; i < n4; i += stride){
    float4 v = ((const float4*)src)[i];
    half4 h; h[0]=(f16)v.x; h[1]=(f16)v.y; h[2]=(f16)v.z; h[3]=(f16)v.w;
    ((half4*)dst)[i] = h;
  }
}

// ---------------- NT GEMM: C[m,n] = sum_k A[m,k]*B[n,k], fp16 in, fp32 acc ----------
// OMODE 0: out f16 = acc + bias[n]                  (projections; gridDim.z==1)
// OMODE 1: out f32 = acc; fused column-stats partials (m,Z) -> f0=pm, f1=pz  (logits S)
// OMODE 3: split-K x4: blockIdx.z = b*4+sp; out fp32 partial plane f0..f3[sp]  (PV)
template<int OMODE>
__global__ __launch_bounds__(256)
void gemm_nt(const f16* __restrict__ A, int lda, long sA,
             const f16* __restrict__ B, int ldb, long sB,
             void* __restrict__ Out, int ldc, long sC,
             const float* __restrict__ aux, int Kdim,
             float* __restrict__ f0, float* __restrict__ f1,
             float* __restrict__ f2, float* __restrict__ f3)
{
  const int sp = (OMODE == 3) ? (blockIdx.z & 3) : 0;
  const int b  = (OMODE == 3) ? (blockIdx.z >> 2) : blockIdx.z;
  const f16* A_ = A + (size_t)b * sA;
  const f16* B_ = B + (size_t)b * sB;
  const int m0 = blockIdx.x * 128, n0 = blockIdx.y * 128;
  const int tid = threadIdx.x, lane = tid & 63;
  const int wave = tid >> 6;
  const int wm = wave >> 1, wn = wave & 1;

  __shared__ f16 lA[128*32];
  __shared__ f16 lB[128*32];
  __shared__ float smx[4][4][16], szx[4][4][16];  // [wave][j][col16] stats scratch

  f32x4 acc[4][4] = {};

  int kbeg = 0, kend = Kdim;
  if constexpr (OMODE == 3){ kbeg = sp * (Kdim >> 2); kend = kbeg + (Kdim >> 2); }

  for (int kt = kbeg; kt < kend; kt += 32){
#pragma unroll
    for (int i = 0; i < 2; ++i){
      int c = i*256 + tid;               // 512 x 16B chunks per 128x32 f16 tile
      int r = c >> 2, col = (c & 3) * 8;
      gload16(A_ + (size_t)(m0 + r) * lda + kt + col, &lA[c*8]);
      gload16(B_ + (size_t)(n0 + r) * ldb + kt + col, &lB[c*8]);
    }
    __syncthreads();   // compiler drains vmcnt before s_barrier

    const int frow = lane & 15, kq = (lane >> 4) * 8;
    half8 af[4], bfr[4];
#pragma unroll
    for (int i = 0; i < 4; ++i){
      af[i]  = *(const half8*)&lA[(wm*64 + i*16 + frow)*32 + kq];
      bfr[i] = *(const half8*)&lB[(wn*64 + i*16 + frow)*32 + kq];
    }
#pragma unroll
    for (int i = 0; i < 4; ++i)
#pragma unroll
      for (int j = 0; j < 4; ++j)
        acc[i][j] = __builtin_amdgcn_mfma_f32_16x16x32_f16(af[i], bfr[j], acc[i][j], 0,0,0);
    __syncthreads();
  }

  // C/D layout: col = lane&15, row = (lane>>4)*4 + r   [m89 verified]
#pragma unroll
  for (int i = 0; i < 4; ++i)
#pragma unroll
    for (int j = 0; j < 4; ++j){
      const int gc = n0 + wn*64 + j*16 + (lane & 15);
      float bias_v = 0.f;
      if constexpr (OMODE == 0) bias_v = aux[gc];
#pragma unroll
      for (int r = 0; r < 4; ++r){
        const int gr = m0 + wm*64 + i*16 + (lane >> 4)*4 + r;
        float v = acc[i][j][r];
        if constexpr (OMODE == 0){
          ((f16*)Out)[(size_t)gr*ldc + gc] = (f16)(v + bias_v);
        } else if constexpr (OMODE == 1){
          ((float*)Out)[(size_t)b*sC + (size_t)gr*ldc + gc] = v;
        } else {
          float* pl = (sp==0) ? f0 : (sp==1) ? f1 : (sp==2) ? f2 : f3;
          pl[(size_t)b*sC + (size_t)gr*ldc + gc] = v;
        }
      }
    }

  if constexpr (OMODE == 1){
    // fused column-stats partial over this block's 128 rows, per column.
    float pmj[4], pzj[4];
#pragma unroll
    for (int j = 0; j < 4; ++j){
      float mx = acc[0][j][0];
#pragma unroll
      for (int i = 0; i < 4; ++i)
#pragma unroll
        for (int r = 0; r < 4; ++r) mx = fmaxf(mx, acc[i][j][r]);
      float zz = 0.f;
#pragma unroll
      for (int i = 0; i < 4; ++i)
#pragma unroll
        for (int r = 0; r < 4; ++r) zz += __expf(acc[i][j][r] - mx);
      // butterfly over lane bits 4,5 (the 4 row-groups share a column)
#pragma unroll
      for (int off = 16; off < 64; off <<= 1){
        float mo = __shfl_xor(mx, off, 64);
        float zo = __shfl_xor(zz, off, 64);
        float M = fmaxf(mx, mo);
        zz = zz*__expf(mx - M) + zo*__expf(mo - M);
        mx = M;
      }
      pmj[j] = mx; pzj[j] = zz;
    }
    if (lane < 16){
#pragma unroll
      for (int j = 0; j < 4; ++j){ smx[wave][j][lane] = pmj[j]; szx[wave][j][lane] = pzj[j]; }
    }
    __syncthreads();
    if (wm == 0 && lane < 16){     // waves 0,1 merge partner waves 2,3 (same wn)
#pragma unroll
      for (int j = 0; j < 4; ++j){
        float m1 = smx[wave + 2][j][lane], z1 = szx[wave + 2][j][lane];
        float M = fmaxf(pmj[j], m1);
        float Z = pzj[j]*__expf(pmj[j] - M) + z1*__expf(m1 - M);
        int gc = n0 + wn*64 + j*16 + lane;
        size_t o = ((size_t)b * NQC + blockIdx.x) * TT + gc;
        f0[o] = M; f1[o] = Z;
      }
    }
  }
}

// ------- merge NQC row-block partials per column -> mcol, zinv -------
__global__ __launch_bounds__(256)
void statsB_kernel(const float* __restrict__ pm, const float* __restrict__ pz,
                   float* __restrict__ mcol, float* __restrict__ zinv){
  const int b = blockIdx.y;
  const int t = blockIdx.x * 256 + threadIdx.x;
  float M = -3.0e38f;
#pragma unroll
  for (int k = 0; k < NQC; ++k)
    M = fmaxf(M, pm[((size_t)b * NQC + k) * TT + t]);
  float Z = 0.f;
#pragma unroll
  for (int k = 0; k < NQC; ++k){
    size_t o = ((size_t)b * NQC + k) * TT + t;
    Z += pz[o] * __expf(pm[o] - M);
  }
  mcol[b*TT + t] = M;
  zinv[b*TT + t] = 1.f / (Z * 27.712812921102035f);  // 1/(Z*sqrt(768))
}

// ---------------- P = exp(S - m_t) * zinv_t -> f16 ----------------
__global__ __launch_bounds__(256)
void pexp_kernel(const float* __restrict__ S, const float* __restrict__ mcol,
                 const float* __restrict__ zinv, f16* __restrict__ P, int G){
  const int n4 = G * (TT*TT/4);
  const int stride = gridDim.x * 256;
  for (int i = blockIdx.x*256 + threadIdx.x; i < n4; i += stride){
    float4 s4 = ((const float4*)S)[i];
    int t   = (i*4) & (TT - 1);
    int row = (int)(((size_t)i * 4) >> 11);   // global row in chunk
    int b   = row >> 11;                      // local batch
    int bt = b * TT + t;
    float4 m4 = *(const float4*)&mcol[bt];
    float4 z4 = *(const float4*)&zinv[bt];
    half4 o;
    o[0] = (f16)(__expf(s4.x - m4.x) * z4.x);
    o[1] = (f16)(__expf(s4.y - m4.y) * z4.y);
    o[2] = (f16)(__expf(s4.z - m4.z) * z4.z);
    o[3] = (f16)(__expf(s4.w - m4.w) * z4.w);
    ((half4*)P)[i] = o;
  }
}

// ---------------- V [t,v] -> Vt [v,t] (per local batch) ----------------
__global__ __launch_bounds__(256)
void transp_kernel(const u16* __restrict__ V, u16* __restrict__ Vt){
  const int b = blockIdx.z;
  const int t0 = blockIdx.x * 64, v0 = blockIdx.y * 64;
  const u16* Vb = V + (size_t)b * TT * DD;
  u16* Vtb = Vt + (size_t)b * DD * TT;
  __shared__ u16 tile[64][66];
  const int tid = threadIdx.x;
#pragma unroll
  for (int i = 0; i < 4; ++i){
    int c = i*256 + tid;
    int r = c >> 4, c4 = (c & 15) * 4;
    ushort4 u = *(const ushort4*)&Vb[(size_t)(t0 + r) * DD + v0 + c4];
    tile[r][c4+0] = u.x; tile[r][c4+1] = u.y; tile[r][c4+2] = u.z; tile[r][c4+3] = u.w;
  }
  __syncthreads();
#pragma unroll
  for (int i = 0; i < 4; ++i){
    int c = i*256 + tid;
    int vr = c >> 4, t4 = (c & 15) * 4;
    ushort4 u;
    u.x = tile[t4+0][vr]; u.y = tile[t4+1][vr]; u.z = tile[t4+2][vr]; u.w = tile[t4+3][vr];
    *(ushort4*)&Vtb[(size_t)(v0 + vr) * TT + t0 + t4] = u;
  }
}

// ------ sum 4 split-K planes + residual x, then LayerNorm, write out ------
// one row per 192-thread block; float4 (16B) lane accesses
__global__ __launch_bounds__(192)
void reduce_ln_kernel(const float4* __restrict__ p0, const float4* __restrict__ p1,
                      const float4* __restrict__ p2, const float4* __restrict__ p3,
                      const float4* __restrict__ xres, const float4* __restrict__ gamma4,
                      const float4* __restrict__ beta4, float4* __restrict__ out){
  const size_t base = (size_t)blockIdx.x * (DD/4);
  const int c = threadIdx.x;            // 0..191
  float4 a = p0[base+c], bq = p1[base+c], cq = p2[base+c], dq = p3[base+c], xr = xres[base+c];
  float y0 = a.x+bq.x+cq.x+dq.x+xr.x;
  float y1 = a.y+bq.y+cq.y+dq.y+xr.y;
  float y2 = a.z+bq.z+cq.z+dq.z+xr.z;
  float y3 = a.w+bq.w+cq.w+dq.w+xr.w;
  float s = y0+y1+y2+y3;
  float sq = y0*y0+y1*y1+y2*y2+y3*y3;
#pragma unroll
  for (int off = 32; off > 0; off >>= 1){
    s  += __shfl_down(s,  off, 64);
    sq += __shfl_down(sq, off, 64);
  }
  __shared__ float rs_[3], rq_[3];
  const int lane = threadIdx.x & 63, w = threadIdx.x >> 6;
  if (lane == 0){ rs_[w] = s; rq_[w] = sq; }
  __syncthreads();
  const float S_ = rs_[0]+rs_[1]+rs_[2];
  const float Q_ = rq_[0]+rq_[1]+rq_[2];
  const float mu  = S_ * (1.f/DD);
  const float var = Q_ * (1.f/DD) - mu*mu;
  const float rstd = rsqrtf(var + 1e-5f);
  float4 g = gamma4[c], be = beta4[c], o;
  o.x = (y0 - mu)*rstd*g.x + be.x;
  o.y = (y1 - mu)*rstd*g.y + be.y;
  o.z = (y2 - mu)*rstd*g.z + be.z;
  o.w = (y3 - mu)*rstd*g.w + be.w;
  out[base+c] = o;
}

extern "C" void kernel_launch(void* const* d_in, const int* in_sizes, int n_in,
                              void* d_out, int out_size, void* d_ws, size_t ws_size,
                              hipStream_t stream)
{
  // setup_inputs order: x, Wk, bk, Wq, bq, Wv, bv, gamma, beta
  const float* x    = (const float*)d_in[0];
  const float* Wk   = (const float*)d_in[1];
  const float* bk   = (const float*)d_in[2];
  const float* Wq   = (const float*)d_in[3];
  const float* bq   = (const float*)d_in[4];
  const float* Wv   = (const float*)d_in[5];
  const float* bv   = (const float*)d_in[6];
  const float* gamma= (const float*)d_in[7];
  const float* beta = (const float*)d_in[8];
  float* out = (float*)d_out;

  const size_t PW  = (size_t)DD*DD*2;   // f16 weight plane
  const size_t PB  = (size_t)TT*DD*2;   // f16 activation plane per batch
  const size_t SB  = (size_t)TT*TT*4;   // f32 S per batch
  const size_t PP  = (size_t)TT*TT*2;   // f16 P per batch
  const size_t TB4 = (size_t)TT*4;

  auto need = [&](int G)->size_t{
    size_t t = 0;
    auto add = [&](size_t n){ t += (n + 255) & ~(size_t)255; };
    add(PW); add(PW); add(PW);
    for (int k = 0; k < 5; ++k) add((size_t)G * PB);   // Xc,Qc,Kc,Vc,Vtc
    add((size_t)G * SB); add((size_t)G * PP);
    add((size_t)G * NQC * TB4); add((size_t)G * NQC * TB4);   // pm, pz
    add((size_t)G * TB4); add((size_t)G * TB4);               // mcol, zinv
    return t;
  };

  int G = 16;
  while (G > 1 && need(G) > ws_size) G >>= 1;
  if (need(G) > ws_size) return;

  char* p = (char*)d_ws;
  auto alloc = [&](size_t n)->char*{ char* r = p; p += (n + 255) & ~(size_t)255; return r; };
  f16*   Wqf  = (f16*)alloc(PW);
  f16*   Wkf  = (f16*)alloc(PW);
  f16*   Wvf  = (f16*)alloc(PW);
  f16*   Xc   = (f16*)alloc((size_t)G * PB);
  f16*   Qc   = (f16*)alloc((size_t)G * PB);
  f16*   Kc   = (f16*)alloc((size_t)G * PB);
  f16*   Vc   = (f16*)alloc((size_t)G * PB);
  f16*   Vtc  = (f16*)alloc((size_t)G * PB);
  float* Sc   = (float*)alloc((size_t)G * SB);
  f16*   Pc   = (f16*)alloc((size_t)G * PP);
  float* pm   = (float*)alloc((size_t)G * NQC * TB4);
  float* pz   = (float*)alloc((size_t)G * NQC * TB4);
  float* mcol = (float*)alloc((size_t)G * TB4);
  float* zinv = (float*)alloc((size_t)G * TB4);

  // split-K partial planes alias buffers that are DEAD during the PV GEMM:
  //   plane0 = Xc..Qc, plane1 = Kc..Vc, planes 2,3 = Sc (each G*TT*DD fp32)
  float* pl0 = (float*)Xc;
  float* pl1 = (float*)Kc;
  float* pl2 = (float*)Sc;
  float* pl3 = (float*)Sc + (size_t)G * TT * DD;

  tofp16_kernel<<<288, 256, 0, stream>>>(Wq, Wqf, DD*DD/4);
  tofp16_kernel<<<288, 256, 0, stream>>>(Wk, Wkf, DD*DD/4);
  tofp16_kernel<<<288, 256, 0, stream>>>(Wv, Wvf, DD*DD/4);

  const int nRows = G * TT;
  for (int b0 = 0; b0 < BB; b0 += G){
    tofp16_kernel<<<2048, 256, 0, stream>>>(x + (size_t)b0*TT*DD, Xc, nRows*DD/4);

    dim3 gp(nRows/128, DD/128, 1);
    gemm_nt<0><<<gp, 256, 0, stream>>>(Xc, DD, 0, Wqf, DD, 0, Qc, DD, 0, bq, DD,
                                       nullptr, nullptr, nullptr, nullptr);
    gemm_nt<0><<<gp, 256, 0, stream>>>(Xc, DD, 0, Wkf, DD, 0, Kc, DD, 0, bk, DD,
                                       nullptr, nullptr, nullptr, nullptr);
    gemm_nt<0><<<gp, 256, 0, stream>>>(Xc, DD, 0, Wvf, DD, 0, Vc, DD, 0, bv, DD,
                                       nullptr, nullptr, nullptr, nullptr);

    transp_kernel<<<dim3(TT/64, DD/64, G), 256, 0, stream>>>((const u16*)Vc, (u16*)Vtc);

    dim3 gs(TT/128, TT/128, G);
    gemm_nt<1><<<gs, 256, 0, stream>>>(Qc, DD, (long)TT*DD, Kc, DD, (long)TT*DD,
                                       Sc, TT, (long)TT*TT, nullptr, DD,
                                       pm, pz, nullptr, nullptr);

    statsB_kernel<<<dim3(TT/256, G), 256, 0, stream>>>(pm, pz, mcol, zinv);
    pexp_kernel<<<2048, 256, 0, stream>>>(Sc, mcol, zinv, Pc, G);

    dim3 gpv(TT/128, DD/128, G*4);   // z = b*4 + split
    gemm_nt<3><<<gpv, 256, 0, stream>>>(Pc, TT, (long)TT*TT, Vtc, TT, (long)DD*TT,
                                        nullptr, DD, (long)TT*DD, nullptr, TT,
                                        pl0, pl1, pl2, pl3);

    reduce_ln_kernel<<<nRows, 192, 0, stream>>>(
        (const float4*)pl0, (const float4*)pl1, (const float4*)pl2, (const float4*)pl3,
        (const float4*)(x + (size_t)b0*TT*DD), (const float4*)gamma, (const float4*)beta,
        (float4*)(out + (size_t)b0*TT*DD));
  }
}

// Round 5
// 814.405 us; speedup vs baseline: 1.4340x; 1.0457x over previous
//
#include <hip/hip_runtime.h>
#include <hip/hip_fp16.h>

// Problem constants (reference: B=16, T=2048, D=768)
#define DD 768
#define BB 16
#define TT 2048
#define BT (BB*TT)   // 32768
#define NQC 16       // row-block partials per batch for column-softmax stats

using u16 = unsigned short;
using f16 = _Float16;
typedef __attribute__((ext_vector_type(8))) f16 half8;   // MFMA A/B frag (4 VGPR)
typedef __attribute__((ext_vector_type(4))) f16 half4;   // 8B store
typedef __attribute__((ext_vector_type(4))) float f32x4; // MFMA C/D frag

typedef const __attribute__((address_space(1))) unsigned int* gas1;
typedef __attribute__((address_space(3))) unsigned int* las3;
__device__ __forceinline__ void gload16(const void* g, void* l){
  // async global->LDS, 16B per lane; LDS dest linear in lane order (wave base + lane*16)
  __builtin_amdgcn_global_load_lds((gas1)g, (las3)l, 16, 0, 0);
}

// ---------------- fp32 -> fp16 ----------------
__global__ __launch_bounds__(256)
void tofp16_kernel(const float* __restrict__ src, f16* __restrict__ dst, int n4){
  const int stride = gridDim.x * 256;
  for (int i = blockIdx.x*256 + threadIdx.x; i < n4; i += stride){
    float4 v = ((const float4*)src)[i];
    half4 h; h[0]=(f16)v.x; h[1]=(f16)v.y; h[2]=(f16)v.z; h[3]=(f16)v.w;
    ((half4*)dst)[i] = h;
  }
}

// ---------------- NT GEMM: C[m,n] = sum_k A[m,k]*B[n,k], fp16 in, fp32 acc ----------
// OMODE 0: merged QKV projections. z = proj index (0..2): B_=W[z], bias=aux[z*DD+..],
//          Out_=base + z*sC, A shared (sA=0). out f16 = acc + bias.
// OMODE 1: out f32 = acc; fused column-stats partials (m,Z) -> f0=pm, f1=pz  (logits S)
// OMODE 2: PV: z = batch. out f32 = acc + res[flat]  (residual x fused)
template<int OMODE>
__global__ __launch_bounds__(256)
void gemm_nt(const f16* __restrict__ A, int lda, long sA,
             const f16* __restrict__ B, int ldb, long sB,
             void* __restrict__ Out, int ldc, long sC,
             const float* __restrict__ aux, int Kdim,
             float* __restrict__ f0, float* __restrict__ f1)
{
  const int b = blockIdx.z;
  const f16* A_ = A + (size_t)b * sA;
  const f16* B_ = B + (size_t)b * sB;
  const int m0 = blockIdx.x * 128, n0 = blockIdx.y * 128;
  const int tid = threadIdx.x, lane = tid & 63;
  const int wave = tid >> 6;
  const int wm = wave >> 1, wn = wave & 1;

  __shared__ f16 lA[128*32];
  __shared__ f16 lB[128*32];
  __shared__ float smx[4][4][16], szx[4][4][16];  // [wave][j][col16] stats scratch

  f32x4 acc[4][4] = {};

  for (int kt = 0; kt < Kdim; kt += 32){
#pragma unroll
    for (int i = 0; i < 2; ++i){
      int c = i*256 + tid;               // 512 x 16B chunks per 128x32 f16 tile
      int r = c >> 2, col = (c & 3) * 8;
      gload16(A_ + (size_t)(m0 + r) * lda + kt + col, &lA[c*8]);
      gload16(B_ + (size_t)(n0 + r) * ldb + kt + col, &lB[c*8]);
    }
    __syncthreads();   // compiler drains vmcnt before s_barrier

    const int frow = lane & 15, kq = (lane >> 4) * 8;
    half8 af[4], bfr[4];
#pragma unroll
    for (int i = 0; i < 4; ++i){
      af[i]  = *(const half8*)&lA[(wm*64 + i*16 + frow)*32 + kq];
      bfr[i] = *(const half8*)&lB[(wn*64 + i*16 + frow)*32 + kq];
    }
#pragma unroll
    for (int i = 0; i < 4; ++i)
#pragma unroll
      for (int j = 0; j < 4; ++j)
        acc[i][j] = __builtin_amdgcn_mfma_f32_16x16x32_f16(af[i], bfr[j], acc[i][j], 0,0,0);
    __syncthreads();
  }

  // C/D layout: col = lane&15, row = (lane>>4)*4 + r   [m89 verified]
#pragma unroll
  for (int i = 0; i < 4; ++i)
#pragma unroll
    for (int j = 0; j < 4; ++j){
      const int gc = n0 + wn*64 + j*16 + (lane & 15);
      float bias_v = 0.f;
      if constexpr (OMODE == 0) bias_v = aux[b*DD + gc];
#pragma unroll
      for (int r = 0; r < 4; ++r){
        const int gr = m0 + wm*64 + i*16 + (lane >> 4)*4 + r;
        float v = acc[i][j][r];
        if constexpr (OMODE == 0){
          ((f16*)Out)[(size_t)b*sC + (size_t)gr*ldc + gc] = (f16)(v + bias_v);
        } else if constexpr (OMODE == 1){
          ((float*)Out)[(size_t)b*sC + (size_t)gr*ldc + gc] = v;
        } else {
          size_t o = (size_t)b*sC + (size_t)gr*ldc + gc;
          ((float*)Out)[o] = v + aux[o];   // aux = residual x, same flat layout
        }
      }
    }

  if constexpr (OMODE == 1){
    // fused column-stats partial over this block's 128 rows, per column.
    float pmj[4], pzj[4];
#pragma unroll
    for (int j = 0; j < 4; ++j){
      float mx = acc[0][j][0];
#pragma unroll
      for (int i = 0; i < 4; ++i)
#pragma unroll
        for (int r = 0; r < 4; ++r) mx = fmaxf(mx, acc[i][j][r]);
      float zz = 0.f;
#pragma unroll
      for (int i = 0; i < 4; ++i)
#pragma unroll
        for (int r = 0; r < 4; ++r) zz += __expf(acc[i][j][r] - mx);
      // butterfly over lane bits 4,5 (the 4 row-groups share a column)
#pragma unroll
      for (int off = 16; off < 64; off <<= 1){
        float mo = __shfl_xor(mx, off, 64);
        float zo = __shfl_xor(zz, off, 64);
        float M = fmaxf(mx, mo);
        zz = zz*__expf(mx - M) + zo*__expf(mo - M);
        mx = M;
      }
      pmj[j] = mx; pzj[j] = zz;
    }
    if (lane < 16){
#pragma unroll
      for (int j = 0; j < 4; ++j){ smx[wave][j][lane] = pmj[j]; szx[wave][j][lane] = pzj[j]; }
    }
    __syncthreads();
    if (wm == 0 && lane < 16){     // waves 0,1 merge partner waves 2,3 (same wn)
#pragma unroll
      for (int j = 0; j < 4; ++j){
        float m1 = smx[wave + 2][j][lane], z1 = szx[wave + 2][j][lane];
        float M = fmaxf(pmj[j], m1);
        float Z = pzj[j]*__expf(pmj[j] - M) + z1*__expf(m1 - M);
        int gc = n0 + wn*64 + j*16 + lane;
        size_t o = ((size_t)b * NQC + blockIdx.x) * TT + gc;
        f0[o] = M; f1[o] = Z;
      }
    }
  }
}

// ------- merge NQC row-block partials per column -> mcol, zinv -------
__global__ __launch_bounds__(256)
void statsB_kernel(const float* __restrict__ pm, const float* __restrict__ pz,
                   float* __restrict__ mcol, float* __restrict__ zinv){
  const int b = blockIdx.y;
  const int t = blockIdx.x * 256 + threadIdx.x;
  float M = -3.0e38f;
#pragma unroll
  for (int k = 0; k < NQC; ++k)
    M = fmaxf(M, pm[((size_t)b * NQC + k) * TT + t]);
  float Z = 0.f;
#pragma unroll
  for (int k = 0; k < NQC; ++k){
    size_t o = ((size_t)b * NQC + k) * TT + t;
    Z += pz[o] * __expf(pm[o] - M);
  }
  mcol[b*TT + t] = M;
  zinv[b*TT + t] = 1.f / (Z * 27.712812921102035f);  // 1/(Z*sqrt(768))
}

// ---------------- P = exp(S - m_t) * zinv_t -> f16 ----------------
__global__ __launch_bounds__(256)
void pexp_kernel(const float* __restrict__ S, const float* __restrict__ mcol,
                 const float* __restrict__ zinv, f16* __restrict__ P, int G){
  const int n4 = G * (TT*TT/4);
  const int stride = gridDim.x * 256;
  for (int i = blockIdx.x*256 + threadIdx.x; i < n4; i += stride){
    float4 s4 = ((const float4*)S)[i];
    int t   = (i*4) & (TT - 1);
    int row = (int)(((size_t)i * 4) >> 11);   // row within chunk
    int b   = row >> 11;                      // local batch
    int bt = b * TT + t;
    float4 m4 = *(const float4*)&mcol[bt];
    float4 z4 = *(const float4*)&zinv[bt];
    half4 o;
    o[0] = (f16)(__expf(s4.x - m4.x) * z4.x);
    o[1] = (f16)(__expf(s4.y - m4.y) * z4.y);
    o[2] = (f16)(__expf(s4.z - m4.z) * z4.z);
    o[3] = (f16)(__expf(s4.w - m4.w) * z4.w);
    ((half4*)P)[i] = o;
  }
}

// ---------------- V [t,v] -> Vt [v,t] (per local batch z) ----------------
__global__ __launch_bounds__(256)
void transp_kernel(const u16* __restrict__ V, u16* __restrict__ Vt){
  const int b = blockIdx.z;
  const int t0 = blockIdx.x * 64, v0 = blockIdx.y * 64;
  const u16* Vb = V + (size_t)b * TT * DD;
  u16* Vtb = Vt + (size_t)b * DD * TT;
  __shared__ u16 tile[64][66];
  const int tid = threadIdx.x;
#pragma unroll
  for (int i = 0; i < 4; ++i){
    int c = i*256 + tid;
    int r = c >> 4, c4 = (c & 15) * 4;
    ushort4 u = *(const ushort4*)&Vb[(size_t)(t0 + r) * DD + v0 + c4];
    tile[r][c4+0] = u.x; tile[r][c4+1] = u.y; tile[r][c4+2] = u.z; tile[r][c4+3] = u.w;
  }
  __syncthreads();
#pragma unroll
  for (int i = 0; i < 4; ++i){
    int c = i*256 + tid;
    int vr = c >> 4, t4 = (c & 15) * 4;
    ushort4 u;
    u.x = tile[t4+0][vr]; u.y = tile[t4+1][vr]; u.z = tile[t4+2][vr]; u.w = tile[t4+3][vr];
    *(ushort4*)&Vtb[(size_t)(v0 + vr) * TT + t0 + t4] = u;
  }
}

// ---------------- LayerNorm (in-place on d_out), one row per block ----------------
__global__ __launch_bounds__(256)
void ln_kernel(float* __restrict__ y, const float* __restrict__ gamma,
               const float* __restrict__ beta){
  const int row = blockIdx.x;
  float* p = y + (size_t)row * DD;
  const int tid = threadIdx.x;
  float v[3]; float s = 0.f, sq = 0.f;
#pragma unroll
  for (int k = 0; k < 3; ++k){
    v[k] = p[tid + k*256];
    s += v[k]; sq += v[k]*v[k];
  }
#pragma unroll
  for (int off = 32; off > 0; off >>= 1){
    s  += __shfl_down(s,  off, 64);
    sq += __shfl_down(sq, off, 64);
  }
  __shared__ float red[8];
  const int lane = tid & 63, w = tid >> 6;
  if (lane == 0){ red[w] = s; red[4+w] = sq; }
  __syncthreads();
  if (tid == 0){
    red[0] = red[0]+red[1]+red[2]+red[3];
    red[4] = red[4]+red[5]+red[6]+red[7];
  }
  __syncthreads();
  const float mu  = red[0] * (1.f/DD);
  const float var = red[4] * (1.f/DD) - mu*mu;
  const float rs  = rsqrtf(var + 1e-5f);
#pragma unroll
  for (int k = 0; k < 3; ++k){
    int c = tid + k*256;
    p[c] = (v[k] - mu) * rs * gamma[c] + beta[c];
  }
}

extern "C" void kernel_launch(void* const* d_in, const int* in_sizes, int n_in,
                              void* d_out, int out_size, void* d_ws, size_t ws_size,
                              hipStream_t stream)
{
  // setup_inputs order: x, Wk, bk, Wq, bq, Wv, bv, gamma, beta
  const float* x    = (const float*)d_in[0];
  const float* Wk   = (const float*)d_in[1];
  const float* bk   = (const float*)d_in[2];
  const float* Wq   = (const float*)d_in[3];
  const float* bq   = (const float*)d_in[4];
  const float* Wv   = (const float*)d_in[5];
  const float* bv   = (const float*)d_in[6];
  const float* gamma= (const float*)d_in[7];
  const float* beta = (const float*)d_in[8];
  float* out = (float*)d_out;

  const size_t PW   = (size_t)DD*DD*2;   // f16 weight plane
  const size_t PB   = (size_t)TT*DD*2;   // f16 activation plane per batch
  const size_t SB   = (size_t)TT*TT*4;   // f32 S per batch
  const size_t PPc  = (size_t)TT*TT*2;   // f16 P per batch
  const size_t T4   = (size_t)TT*4;
  auto al = [](size_t n){ return (n + 255) & ~(size_t)255; };

  // full-PV layout: Vt + P are full-batch; X/Q/K/V/S chunked by G
  auto needFull = [&](int G)->size_t{
    return al(3*PW) + al(3*DD*4) + al((size_t)BB*PB) + al((size_t)BB*PPc)
         + 4*al((size_t)G*PB) + al((size_t)G*SB)
         + 2*al((size_t)G*NQC*T4) + 2*al((size_t)G*T4);
  };
  // fallback: everything chunked (PV per chunk, no split-K)
  auto needFb = [&](int G)->size_t{
    return al(3*PW) + al(3*DD*4) + al((size_t)G*PB) + al((size_t)G*PPc)
         + 4*al((size_t)G*PB) + al((size_t)G*SB)
         + 2*al((size_t)G*NQC*T4) + 2*al((size_t)G*T4);
  };

  int G = 0; bool fullPV = false;
  for (int g : {4, 2, 1}) if (needFull(g) <= ws_size){ G = g; fullPV = true; break; }
  if (!fullPV) for (int g : {4, 2, 1}) if (needFb(g) <= ws_size){ G = g; break; }
  if (G == 0) return;

  char* p = (char*)d_ws;
  auto alloc = [&](size_t n)->char*{ char* r = p; p += (n + 255) & ~(size_t)255; return r; };
  f16*   Wf    = (f16*)alloc(3*PW);            // [Wq;Wk;Wv] stacked
  float* biasf = (float*)alloc(3*DD*4);        // [bq;bk;bv] stacked
  f16*   Vt    = (f16*)alloc((fullPV ? (size_t)BB : (size_t)G) * PB);
  f16*   P     = (f16*)alloc((fullPV ? (size_t)BB : (size_t)G) * PPc);
  f16*   Xc    = (f16*)alloc((size_t)G * PB);
  f16*   QKVc  = (f16*)alloc(3*(size_t)G * PB);     // Q,K,V contiguous chunk planes
  float* Sc    = (float*)alloc((size_t)G * SB);
  float* pm    = (float*)alloc((size_t)G * NQC * T4);
  float* pz    = (float*)alloc((size_t)G * NQC * T4);
  float* mcol  = (float*)alloc((size_t)G * T4);
  float* zinv  = (float*)alloc((size_t)G * T4);
  f16* Qc = QKVc, *Kc = QKVc + (size_t)G*TT*DD, *Vc = QKVc + 2*(size_t)G*TT*DD;

  tofp16_kernel<<<288, 256, 0, stream>>>(Wq, Wf,             DD*DD/4);
  tofp16_kernel<<<288, 256, 0, stream>>>(Wk, Wf +   DD*DD,   DD*DD/4);
  tofp16_kernel<<<288, 256, 0, stream>>>(Wv, Wf + 2*DD*DD,   DD*DD/4);
  hipMemcpyAsync(biasf,        bq, DD*4, hipMemcpyDeviceToDevice, stream);
  hipMemcpyAsync(biasf +   DD, bk, DD*4, hipMemcpyDeviceToDevice, stream);
  hipMemcpyAsync(biasf + 2*DD, bv, DD*4, hipMemcpyDeviceToDevice, stream);

  const int nRows = G * TT;
  for (int b0 = 0; b0 < BB; b0 += G){
    tofp16_kernel<<<2048, 256, 0, stream>>>(x + (size_t)b0*TT*DD, Xc, nRows*DD/4);

    // merged Q,K,V projections: z = proj index
    dim3 gp(nRows/128, DD/128, 3);
    gemm_nt<0><<<gp, 256, 0, stream>>>(Xc, DD, 0, Wf, DD, (long)DD*DD,
                                       QKVc, DD, (long)G*TT*DD, biasf, DD,
                                       nullptr, nullptr);

    transp_kernel<<<dim3(TT/64, DD/64, G), 256, 0, stream>>>(
        (const u16*)Vc, (u16*)(Vt + (fullPV ? (size_t)b0*DD*TT : 0)));

    dim3 gs(TT/128, TT/128, G);
    gemm_nt<1><<<gs, 256, 0, stream>>>(Qc, DD, (long)TT*DD, Kc, DD, (long)TT*DD,
                                       Sc, TT, (long)TT*TT, nullptr, DD, pm, pz);

    statsB_kernel<<<dim3(TT/256, G), 256, 0, stream>>>(pm, pz, mcol, zinv);
    pexp_kernel<<<2048, 256, 0, stream>>>(Sc, mcol, zinv,
                                          P + (fullPV ? (size_t)b0*TT*TT : 0), G);

    if (!fullPV){
      dim3 gpv(TT/128, DD/128, G);
      gemm_nt<2><<<gpv, 256, 0, stream>>>(P, TT, (long)TT*TT, Vt, TT, (long)DD*TT,
                                          out + (size_t)b0*TT*DD, DD, (long)TT*DD,
                                          x + (size_t)b0*TT*DD, TT, nullptr, nullptr);
    }
  }

  if (fullPV){
    dim3 gpv(TT/128, DD/128, BB);   // one dispatch, 1536 blocks
    gemm_nt<2><<<gpv, 256, 0, stream>>>(P, TT, (long)TT*TT, Vt, TT, (long)DD*TT,
                                        out, DD, (long)TT*DD, x, TT, nullptr, nullptr);
  }

  ln_kernel<<<BT, 256, 0, stream>>>(out, gamma, beta);
}